// Round 8
// baseline (1860.627 us; speedup 1.0000x reference)
//
#include <hip/hip_runtime.h>
#include <math.h>

// Problem constants
#define PN   20000
#define PNE  80000
#define PT   6
#define PE   10
#define PIN  256
#define PH1  128
#define PH2  64
#define PC   6
#define NSEG (PT * PN)          // 120000 segments
#define NED  (PE * PNE)         // 800000 edges

// SRC_T[e] = e<5 ? e+1 : 0 ;  DST_T[e] = e<5 ? 0 : e-4
// kqv split order: k = cols[0:H], q = cols[H:2H], v = cols[2H:3H]

__device__ __forceinline__ float gelu_f(float v)
{
  return 0.5f * v * (1.f + erff(v * 0.70710678118654752f));
}

// ---------------------------------------------------------------------------
// Generic tiled fp32 GEMM: C = A(MxK) * B(KxN) [+ bias], 64x64 tile, 4x4/thr
// ---------------------------------------------------------------------------
#define TS  64
#define BKK 16

template <bool GELU_A>
__device__ __forceinline__ void gemm_block(
    const float* __restrict__ A, int lda,
    const float* __restrict__ B, int ldb,
    const float* __restrict__ bias,     // may be nullptr
    float* __restrict__ C, int ldc,
    int M, int K)
{
  __shared__ float As[BKK][TS];   // [k][row]
  __shared__ float Bs[BKK][TS];   // [k][col]

  const int tid  = threadIdx.x;        // 0..255
  const int tx   = tid & 15;
  const int ty   = tid >> 4;
  const int row0 = blockIdx.x * TS;
  const int col0 = blockIdx.y * TS;

  float acc[4][4] = {};

  const int rowA = tid >> 2;           // 0..63
  const int kA   = (tid & 3) * 4;      // 0,4,8,12
  const int colB = tid & 63;
  const int kB   = tid >> 6;           // 0..3

  for (int k0 = 0; k0 < K; k0 += BKK) {
    float4 a4;
    const int gr = row0 + rowA;
    if (gr < M) a4 = *(const float4*)(A + (size_t)gr * lda + k0 + kA);
    else        a4 = make_float4(0.f, 0.f, 0.f, 0.f);
    if (GELU_A) {
      a4.x = gelu_f(a4.x); a4.y = gelu_f(a4.y);
      a4.z = gelu_f(a4.z); a4.w = gelu_f(a4.w);
    }

    __syncthreads();   // previous compute done before overwrite
    As[kA + 0][rowA] = a4.x;
    As[kA + 1][rowA] = a4.y;
    As[kA + 2][rowA] = a4.z;
    As[kA + 3][rowA] = a4.w;
    #pragma unroll
    for (int p = 0; p < 4; ++p) {
      const int kk = kB + p * 4;
      Bs[kk][colB] = B[(size_t)(k0 + kk) * ldb + col0 + colB];
    }
    __syncthreads();

    #pragma unroll
    for (int kk = 0; kk < BKK; ++kk) {
      const float4 av = *(const float4*)&As[kk][ty * 4];
      const float4 bv = *(const float4*)&Bs[kk][tx * 4];
      acc[0][0] += av.x * bv.x; acc[0][1] += av.x * bv.y;
      acc[0][2] += av.x * bv.z; acc[0][3] += av.x * bv.w;
      acc[1][0] += av.y * bv.x; acc[1][1] += av.y * bv.y;
      acc[1][2] += av.y * bv.z; acc[1][3] += av.y * bv.w;
      acc[2][0] += av.z * bv.x; acc[2][1] += av.z * bv.y;
      acc[2][2] += av.z * bv.z; acc[2][3] += av.z * bv.w;
      acc[3][0] += av.w * bv.x; acc[3][1] += av.w * bv.y;
      acc[3][2] += av.w * bv.z; acc[3][3] += av.w * bv.w;
    }
  }

  float b4[4] = {0.f, 0.f, 0.f, 0.f};
  if (bias) {
    #pragma unroll
    for (int j = 0; j < 4; ++j) b4[j] = bias[col0 + tx * 4 + j];
  }
  #pragma unroll
  for (int i = 0; i < 4; ++i) {
    const int gr = row0 + ty * 4 + i;
    if (gr < M) {
      float4 o;
      o.x = acc[i][0] + b4[0];
      o.y = acc[i][1] + b4[1];
      o.z = acc[i][2] + b4[2];
      o.w = acc[i][3] + b4[3];
      *(float4*)(C + (size_t)gr * ldc + col0 + tx * 4) = o;
    }
  }
}

// one H-wide slice (s: 0=k,1=q,2=v) of the kqv projection for all T types
__global__ __launch_bounds__(256) void k_gemm_slice(
    const float* __restrict__ X, const float* __restrict__ W,
    const float* __restrict__ b, float* __restrict__ out,
    int M, int K, int threeH, int s, int H)
{
  const int t = blockIdx.z;
  gemm_block<false>(X + (size_t)t * M * K, K,
                    W + (size_t)t * K * threeH + (size_t)s * H, threeH,
                    b + (size_t)t * threeH + (size_t)s * H,
                    out + (size_t)t * M * H, H, M, K);
}

// rel transform: dst[e] = S[SRC_T[e]] @ R[e]   (S is [T][M][H])
__global__ __launch_bounds__(256) void k_gemm_rel(
    const float* __restrict__ S, const float* __restrict__ R,
    float* __restrict__ dst, int M, int H)
{
  const int e  = blockIdx.z;
  const int sT = (e < 5) ? e + 1 : 0;
  gemm_block<false>(S + (size_t)sT * M * H, H,
                    R + (size_t)e * H * H, H, nullptr,
                    dst + (size_t)e * M * H, H, M, H);
}

// out[t] = gelu(h[t]) @ Wout[t] + bout[t]   (GELU fused into A-load)
__global__ __launch_bounds__(256) void k_gemm_out(
    const float* __restrict__ Hm, const float* __restrict__ W,
    const float* __restrict__ b, float* __restrict__ out,
    int M, int H)
{
  const int t = blockIdx.z;
  gemm_block<true>(Hm + (size_t)t * M * H, H,
                   W + (size_t)t * H * H, H,
                   b + (size_t)t * H,
                   out + (size_t)t * M * H, H, M, H);
}

// ---------------------------------------------------------------------------
// CSR build: segment (dT*PN+dst) -> list of packed (e*PN+src)
// ---------------------------------------------------------------------------
__global__ __launch_bounds__(256) void k_csr_zero(int* __restrict__ deg, int* __restrict__ cur)
{
  const int i = blockIdx.x * 256 + threadIdx.x;
  if (i < NSEG) { deg[i] = 0; cur[i] = 0; }
}

__global__ __launch_bounds__(256) void k_csr_count(
    const int* __restrict__ eidx, int* __restrict__ deg)
{
  const int gid = blockIdx.x * 256 + threadIdx.x;   // grid = NED/256 exactly
  const int e   = gid / PNE;
  const int j   = gid - e * PNE;
  const int dst = eidx[(size_t)e * 2 * PNE + PNE + j];
  const int dT  = (e < 5) ? 0 : e - 4;
  atomicAdd(&deg[dT * PN + dst], 1);
}

// single-block exclusive scan over NSEG entries -> offs[NSEG+1]
__global__ __launch_bounds__(1024) void k_csr_scan(
    const int* __restrict__ deg, int* __restrict__ offs)
{
  __shared__ int part[1024];
  const int tid   = threadIdx.x;
  const int chunk = (NSEG + 1023) / 1024;           // 118
  const int lo    = tid * chunk;
  const int hi    = (lo + chunk < NSEG) ? lo + chunk : NSEG;

  int s = 0;
  for (int i = lo; i < hi; ++i) s += deg[i];
  part[tid] = s;
  __syncthreads();
  for (int off = 1; off < 1024; off <<= 1) {
    int v = (tid >= off) ? part[tid - off] : 0;
    __syncthreads();
    part[tid] += v;
    __syncthreads();
  }
  int base = (tid == 0) ? 0 : part[tid - 1];
  for (int i = lo; i < hi; ++i) { offs[i] = base; base += deg[i]; }
  if (tid == 1023) offs[NSEG] = base;               // total = NED
}

__global__ __launch_bounds__(256) void k_csr_fill(
    const int* __restrict__ eidx, const int* __restrict__ offs,
    int* __restrict__ cur, int* __restrict__ val)
{
  const int gid = blockIdx.x * 256 + threadIdx.x;   // grid = NED/256
  const int e   = gid / PNE;
  const int j   = gid - e * PNE;
  const int src = eidx[(size_t)e * 2 * PNE + j];
  const int dst = eidx[(size_t)e * 2 * PNE + PNE + j];
  const int dT  = (e < 5) ? 0 : e - 4;
  const int seg = dT * PN + dst;
  const int pos = offs[seg] + atomicAdd(&cur[seg], 1);
  val[pos] = e * PN + src;                          // packed: directly indexes ktr/vtr rows
}

// ---------------------------------------------------------------------------
// Fused edge attention: one wave per segment. No global atomics, no init.
// q is a dedicated [T][PN][H] buffer (contiguous rows).
// ---------------------------------------------------------------------------
#define ACAP 256

template <int H>
__global__ __launch_bounds__(256) void k_attn_fused(
    const float* __restrict__ q,       // [NSEG][H]
    const float* __restrict__ ktr,     // [(e*PN+src)][H]
    const float* __restrict__ vtr,
    const int*   __restrict__ offs,
    const int*   __restrict__ csr_val,
    const float* __restrict__ p_rel,
    float*       __restrict__ agg)     // [NSEG][H]
{
  const int seg  = blockIdx.x * 4 + (threadIdx.x >> 6);
  const int lane = threadIdx.x & 63;
  const int wv   = threadIdx.x >> 6;
  constexpr int PL = H / 64;           // floats per lane
  const float scale = 1.0f / sqrtf((float)H);

  __shared__ float salpha[4][ACAP];
  float* lalpha = salpha[wv];

  const float* qrow = q + (size_t)seg * H;
  float qr[PL];
  #pragma unroll
  for (int p = 0; p < PL; ++p) qr[p] = qrow[lane + 64 * p];

  const int start = offs[seg];
  const int deg   = offs[seg + 1] - start;

  // pass 1: alphas + running max (alpha broadcast to all lanes via butterfly)
  float m = -INFINITY;
  for (int i = 0; i < deg; ++i) {
    const int val = csr_val[start + i];
    const int e   = val / PN;
    const float* krow = ktr + (size_t)val * H;
    float d = 0.f;
    #pragma unroll
    for (int p = 0; p < PL; ++p) d += qr[p] * krow[lane + 64 * p];
    #pragma unroll
    for (int off = 32; off > 0; off >>= 1) d += __shfl_xor(d, off);
    const float al = d * p_rel[e] * scale;
    if (i < ACAP && lane == 0) lalpha[i] = al;
    m = fmaxf(m, al);
  }

  // pass 2: exp, sum, weighted-V accumulate
  float acc[PL];
  #pragma unroll
  for (int p = 0; p < PL; ++p) acc[p] = 0.f;
  float s = 0.f;
  for (int i = 0; i < deg; ++i) {
    const int val = csr_val[start + i];
    float al;
    if (i < ACAP) {
      al = lalpha[i];
    } else {                            // fallback (deg > 256: practically never)
      const int e = val / PN;
      const float* krow = ktr + (size_t)val * H;
      float d = 0.f;
      #pragma unroll
      for (int p = 0; p < PL; ++p) d += qr[p] * krow[lane + 64 * p];
      #pragma unroll
      for (int off = 32; off > 0; off >>= 1) d += __shfl_xor(d, off);
      al = d * p_rel[e] * scale;
    }
    const float ev = expf(al - m);
    s += ev;
    const float* vrow = vtr + (size_t)val * H;
    #pragma unroll
    for (int p = 0; p < PL; ++p) acc[p] += ev * vrow[lane + 64 * p];
  }

  const float inv = 1.0f / (s + 1e-16f);
  float* arow = agg + (size_t)seg * H;
  #pragma unroll
  for (int p = 0; p < PL; ++p) arow[lane + 64 * p] = acc[p] * inv;
}

// epilogue: tanh -> rel/all_rep, logits = all_rep @ W3 + b3.  one wave per row.
__global__ __launch_bounds__(256) void k_final(
    const float* __restrict__ h2, const float* __restrict__ W3,
    const float* __restrict__ b3, float* __restrict__ out)
{
  const int row = blockIdx.x * 4 + (threadIdx.x >> 6);
  if (row >= PT * PN) return;
  const int lane = threadIdx.x & 63;

  const float v = tanhf(h2[(size_t)row * PH2 + lane]);
  out[(size_t)PN * PH2 + (size_t)row * PH2 + lane] = v;      // all_rep
  if (row < PN) out[(size_t)row * PH2 + lane] = v;           // rel

  float l[PC];
  #pragma unroll
  for (int c = 0; c < PC; ++c) l[c] = v * W3[lane * PC + c];
  #pragma unroll
  for (int c = 0; c < PC; ++c) {
    #pragma unroll
    for (int off = 32; off > 0; off >>= 1) l[c] += __shfl_xor(l[c], off);
  }
  if (lane == 0) {
    const size_t lo = (size_t)PN * PH2 + (size_t)PT * PN * PH2;
    #pragma unroll
    for (int c = 0; c < PC; ++c) out[lo + (size_t)row * PC + c] = l[c] + b3[c];
  }
}

// diagnostic fallback: ws too small -> deterministic zero output (no OOB, no crash)
__global__ __launch_bounds__(256) void k_out_zero(float* __restrict__ out, long n)
{
  const long i = (long)blockIdx.x * 256 + threadIdx.x;
  if (i < n) out[i] = 0.f;
}

// ---------------------------------------------------------------------------
extern "C" void kernel_launch(void* const* d_in, const int* in_sizes, int n_in,
                              void* d_out, int out_size, void* d_ws, size_t ws_size,
                              hipStream_t stream)
{
  const float* x      = (const float*)d_in[0];
  const int*   eidx   = (const int*)  d_in[1];
  const float* Wkqv1  = (const float*)d_in[2];
  const float* bkqv1  = (const float*)d_in[3];
  const float* a1     = (const float*)d_in[4];
  const float* m1     = (const float*)d_in[5];
  const float* p1     = (const float*)d_in[6];
  const float* Wout1  = (const float*)d_in[7];
  const float* bout1  = (const float*)d_in[8];
  const float* Wkqv2  = (const float*)d_in[9];
  const float* bkqv2  = (const float*)d_in[10];
  const float* a2     = (const float*)d_in[11];
  const float* m2     = (const float*)d_in[12];
  const float* p2     = (const float*)d_in[13];
  const float* Wout2  = (const float*)d_in[14];
  const float* bout2  = (const float*)d_in[15];
  const float* W3     = (const float*)d_in[16];
  const float* b3     = (const float*)d_in[17];
  float* out = (float*)d_out;

  // -------- tight workspace layout: 332.3 MB total --------
  // A(102.4M): ktr1 -> ktr2          B(102.4M): vtr1 -> vtr2
  // C(61.44M): k1 -> v1 -> q1 -> x2(no! x2 goes here) ... see schedule below
  // D(61.44M): agg1 -> k2 -> v2 -> q2 -> h2o
  const size_t SZ_A = (size_t)PE * PN * PH1 * 4;     // 102,400,000
  const size_t SZ_B = SZ_A;
  const size_t SZ_C = (size_t)PT * PN * PH1 * 4;     //  61,440,000
  const size_t SZ_D = SZ_C;
  const size_t R_A = 0;
  const size_t R_B = R_A + SZ_A;
  const size_t R_C = R_B + SZ_B;
  const size_t R_D = R_C + SZ_C;
  const size_t R_deg  = R_D + SZ_D;
  const size_t R_offs = R_deg  + (size_t)NSEG * 4;
  const size_t R_cur  = R_offs + (size_t)(NSEG + 1) * 4;
  const size_t R_val  = R_cur  + (size_t)NSEG * 4;
  const size_t NEED   = R_val + (size_t)NED * 4;     // 332,320,004 bytes

  if (ws_size < NEED) {                              // diagnostic: clean fail, no OOB
    const long n = out_size;
    k_out_zero<<<dim3((unsigned)((n + 255) / 256)), dim3(256), 0, stream>>>(out, n);
    return;
  }

  char* ws = (char*)d_ws;
  float* bufA = (float*)(ws + R_A);
  float* bufB = (float*)(ws + R_B);
  float* bufC = (float*)(ws + R_C);
  float* bufD = (float*)(ws + R_D);
  int*   deg  = (int*)  (ws + R_deg);
  int*   offs = (int*)  (ws + R_offs);
  int*   cur  = (int*)  (ws + R_cur);
  int*   cval = (int*)  (ws + R_val);

  const dim3 blk(256);
  const int  mt = (PN + TS - 1) / TS;          // 313 row tiles

  // ---------------- CSR build (shared by both layers) ----------------
  k_csr_zero <<<dim3((NSEG + 255) / 256), blk, 0, stream>>>(deg, cur);
  k_csr_count<<<dim3(NED / 256), blk, 0, stream>>>(eidx, deg);
  k_csr_scan <<<dim3(1), dim3(1024), 0, stream>>>(deg, offs);
  k_csr_fill <<<dim3(NED / 256), blk, 0, stream>>>(eidx, offs, cur, cval);

  // ---------------- Layer 1 (H=128) ----------------
  // 1. k1 -> C ; 2. ktr1 = k1@a1 -> A ; 3. v1 -> C ; 4. vtr1 = v1@m1 -> B
  // 5. q1 -> C ; 6. attn -> agg1 -> D ; 7. x2 = gelu(agg1)@Wout1 -> C
  k_gemm_slice<<<dim3(mt, PH1 / TS, PT), blk, 0, stream>>>(x, Wkqv1, bkqv1, bufC, PN, PIN, 3 * PH1, 0, PH1);
  k_gemm_rel  <<<dim3(mt, PH1 / TS, PE), blk, 0, stream>>>(bufC, a1, bufA, PN, PH1);
  k_gemm_slice<<<dim3(mt, PH1 / TS, PT), blk, 0, stream>>>(x, Wkqv1, bkqv1, bufC, PN, PIN, 3 * PH1, 2, PH1);
  k_gemm_rel  <<<dim3(mt, PH1 / TS, PE), blk, 0, stream>>>(bufC, m1, bufB, PN, PH1);
  k_gemm_slice<<<dim3(mt, PH1 / TS, PT), blk, 0, stream>>>(x, Wkqv1, bkqv1, bufC, PN, PIN, 3 * PH1, 1, PH1);
  k_attn_fused<PH1><<<dim3(NSEG / 4), blk, 0, stream>>>(bufC, bufA, bufB, offs, cval, p1, bufD);
  k_gemm_out  <<<dim3(mt, PH1 / TS, PT), blk, 0, stream>>>(bufD, Wout1, bout1, bufC, PN, PH1);

  // ---------------- Layer 2 (H=64), x2 in C ----------------
  // 8. k2 -> D ; 9. ktr2 -> A ; 10. v2 -> D ; 11. vtr2 -> B ; 12. q2 -> D
  // 13. attn -> agg2 -> ...  x2 dead after 12, but agg2 must not overwrite q2(D):
  //     place agg2 in C (x2 dead) ; 14. h2o = gelu(agg2)@Wout2 -> D
  k_gemm_slice<<<dim3(mt, PH2 / TS, PT), blk, 0, stream>>>(bufC, Wkqv2, bkqv2, bufD, PN, PH1, 3 * PH2, 0, PH2);
  k_gemm_rel  <<<dim3(mt, PH2 / TS, PE), blk, 0, stream>>>(bufD, a2, bufA, PN, PH2);
  k_gemm_slice<<<dim3(mt, PH2 / TS, PT), blk, 0, stream>>>(bufC, Wkqv2, bkqv2, bufD, PN, PH1, 3 * PH2, 2, PH2);
  k_gemm_rel  <<<dim3(mt, PH2 / TS, PE), blk, 0, stream>>>(bufD, m2, bufB, PN, PH2);
  k_gemm_slice<<<dim3(mt, PH2 / TS, PT), blk, 0, stream>>>(bufC, Wkqv2, bkqv2, bufD, PN, PH1, 3 * PH2, 1, PH2);
  k_attn_fused<PH2><<<dim3(NSEG / 4), blk, 0, stream>>>(bufD, bufA, bufB, offs, cval, p2, bufC);
  k_gemm_out  <<<dim3(mt, PH2 / TS, PT), blk, 0, stream>>>(bufC, Wout2, bout2, bufD, PN, PH2);

  // ---------------- Epilogue ----------------
  k_final<<<dim3((PT * PN + 3) / 4), blk, 0, stream>>>(bufD, W3, b3, out);
}

// Round 11
// 1300.574 us; speedup vs baseline: 1.4306x; 1.4306x over previous
//
#include <hip/hip_runtime.h>
#include <math.h>

// Problem constants
#define PN   20000
#define PNE  80000
#define PT   6
#define PE   10
#define PIN  256
#define PH1  128
#define PH2  64
#define PC   6
#define NSEG (PT * PN)          // 120000 segments
#define NED  (PE * PNE)         // 800000 edges

// SRC_T[e] = e<5 ? e+1 : 0 ;  DST_T[e] = e<5 ? 0 : e-4
// kqv split order: k = cols[0:H], q = cols[H:2H], v = cols[2H:3H]

typedef _Float16 f16x8 __attribute__((ext_vector_type(8)));
typedef float    f32x4 __attribute__((ext_vector_type(4)));

__device__ __forceinline__ float gelu_f(float v)
{
  return 0.5f * v * (1.f + erff(v * 0.70710678118654752f));
}

// ---------------------------------------------------------------------------
// MFMA fp16 GEMM: C = A(MxK)@B(KxN) [+bias], fp32 accum.
// 64x64 tile, 4 waves (2x2), each wave 32x32 via 2x2 mfma_f32_16x16x32_f16.
// A staged [row][k] fp16, B staged [col][k] fp16 (transposed). +8 pad: 16B rows.
// frag: row/col = lane&15, k = 8*(lane>>4)+i ; C/D: col=lane&15,
// row=(lane>>4)*4+reg  [m89 layout].
// ---------------------------------------------------------------------------
template <bool GELU_A>
__device__ __forceinline__ void mfma_gemm_block(
    const float* __restrict__ A, int lda,
    const float* __restrict__ B, int ldb,
    const float* __restrict__ bias,     // may be nullptr
    float* __restrict__ C, int ldc,
    int M, int K)
{
  __shared__ _Float16 As[64][40];
  __shared__ _Float16 Bs[64][40];

  const int tid  = threadIdx.x;
  const int lane = tid & 63;
  const int w    = tid >> 6;       // wave 0..3
  const int wr   = w >> 1;         // wave row 0..1
  const int wc   = w & 1;          // wave col 0..1
  const int row0 = blockIdx.x * 64;
  const int col0 = blockIdx.y * 64;

  f32x4 acc[2][2] = {};

  const int arow = tid >> 2;       // 0..63
  const int akk  = (tid & 3) * 8;  // 0,8,16,24
  const int bcol = tid & 63;
  const int bkk  = w * 8;          // 0,8,16,24

  const int fr = lane & 15;        // fragment row/col
  const int fk = (lane >> 4) * 8;  // fragment k-offset
  const int cr = (lane >> 4) * 4;  // C/D row base

  for (int k0 = 0; k0 < K; k0 += 32) {
    // ---- global loads (fp32) ----
    float av[8] = {0.f,0.f,0.f,0.f,0.f,0.f,0.f,0.f};
    const int gr = row0 + arow;
    if (gr < M) {
      const float4 x0 = *(const float4*)(A + (size_t)gr * lda + k0 + akk);
      const float4 x1 = *(const float4*)(A + (size_t)gr * lda + k0 + akk + 4);
      av[0]=x0.x; av[1]=x0.y; av[2]=x0.z; av[3]=x0.w;
      av[4]=x1.x; av[5]=x1.y; av[6]=x1.z; av[7]=x1.w;
      if (GELU_A) {
        #pragma unroll
        for (int i = 0; i < 8; ++i) av[i] = gelu_f(av[i]);
      }
    }
    float bv[8];
    #pragma unroll
    for (int i = 0; i < 8; ++i)
      bv[i] = B[(size_t)(k0 + bkk + i) * ldb + col0 + bcol];

    // ---- stage to LDS as fp16 ----
    __syncthreads();   // previous iteration's reads done
    f16x8 ah, bh;
    #pragma unroll
    for (int i = 0; i < 8; ++i) ah[i] = (_Float16)av[i];
    #pragma unroll
    for (int i = 0; i < 8; ++i) bh[i] = (_Float16)bv[i];
    *(f16x8*)&As[arow][akk] = ah;
    *(f16x8*)&Bs[bcol][bkk] = bh;
    __syncthreads();

    // ---- MFMA ----
    #pragma unroll
    for (int m = 0; m < 2; ++m) {
      const f16x8 af = *(const f16x8*)&As[wr*32 + m*16 + fr][fk];
      #pragma unroll
      for (int n = 0; n < 2; ++n) {
        const f16x8 bf = *(const f16x8*)&Bs[wc*32 + n*16 + fr][fk];
        acc[m][n] = __builtin_amdgcn_mfma_f32_16x16x32_f16(af, bf, acc[m][n], 0, 0, 0);
      }
    }
  }

  // ---- epilogue (fp32 bias + store) ----
  #pragma unroll
  for (int m = 0; m < 2; ++m) {
    #pragma unroll
    for (int n = 0; n < 2; ++n) {
      const int col = col0 + wc*32 + n*16 + fr;
      const float bb = bias ? bias[col] : 0.f;
      #pragma unroll
      for (int r = 0; r < 4; ++r) {
        const int row = row0 + wr*32 + m*16 + cr + r;
        if (row < M) C[(size_t)row * ldc + col] = acc[m][n][r] + bb;
      }
    }
  }
}

// one H-wide slice (s: 0=k,1=q,2=v) of the kqv projection for all T types
__global__ __launch_bounds__(256) void k_gemm_slice(
    const float* __restrict__ X, const float* __restrict__ W,
    const float* __restrict__ b, float* __restrict__ out,
    int M, int K, int threeH, int s, int H)
{
  const int t = blockIdx.z;
  mfma_gemm_block<false>(X + (size_t)t * M * K, K,
                         W + (size_t)t * K * threeH + (size_t)s * H, threeH,
                         b + (size_t)t * threeH + (size_t)s * H,
                         out + (size_t)t * M * H, H, M, K);
}

// rel transform: dst[e] = S[SRC_T[e]] @ R[e]   (S is [T][M][H])
__global__ __launch_bounds__(256) void k_gemm_rel(
    const float* __restrict__ S, const float* __restrict__ R,
    float* __restrict__ dst, int M, int H)
{
  const int e  = blockIdx.z;
  const int sT = (e < 5) ? e + 1 : 0;
  mfma_gemm_block<false>(S + (size_t)sT * M * H, H,
                         R + (size_t)e * H * H, H, nullptr,
                         dst + (size_t)e * M * H, H, M, H);
}

// out[t] = gelu(h[t]) @ Wout[t] + bout[t]   (GELU fused into A-staging)
__global__ __launch_bounds__(256) void k_gemm_out(
    const float* __restrict__ Hm, const float* __restrict__ W,
    const float* __restrict__ b, float* __restrict__ out,
    int M, int H)
{
  const int t = blockIdx.z;
  mfma_gemm_block<true>(Hm + (size_t)t * M * H, H,
                        W + (size_t)t * H * H, H,
                        b + (size_t)t * H,
                        out + (size_t)t * M * H, H, M, H);
}

// ---------------------------------------------------------------------------
// CSR build: segment (dT*PN+dst) -> list of packed (e*PN+src)
// ---------------------------------------------------------------------------
__global__ __launch_bounds__(256) void k_csr_zero(int* __restrict__ deg, int* __restrict__ cur)
{
  const int i = blockIdx.x * 256 + threadIdx.x;
  if (i < NSEG) { deg[i] = 0; cur[i] = 0; }
}

__global__ __launch_bounds__(256) void k_csr_count(
    const int* __restrict__ eidx, int* __restrict__ deg)
{
  const int gid = blockIdx.x * 256 + threadIdx.x;   // grid = NED/256 exactly
  const int e   = gid / PNE;
  const int j   = gid - e * PNE;
  const int dst = eidx[(size_t)e * 2 * PNE + PNE + j];
  const int dT  = (e < 5) ? 0 : e - 4;
  atomicAdd(&deg[dT * PN + dst], 1);
}

// single-block exclusive scan over NSEG entries -> offs[NSEG+1]
__global__ __launch_bounds__(1024) void k_csr_scan(
    const int* __restrict__ deg, int* __restrict__ offs)
{
  __shared__ int part[1024];
  const int tid   = threadIdx.x;
  const int chunk = (NSEG + 1023) / 1024;           // 118
  const int lo    = tid * chunk;
  const int hi    = (lo + chunk < NSEG) ? lo + chunk : NSEG;

  int s = 0;
  for (int i = lo; i < hi; ++i) s += deg[i];
  part[tid] = s;
  __syncthreads();
  for (int off = 1; off < 1024; off <<= 1) {
    int v = (tid >= off) ? part[tid - off] : 0;
    __syncthreads();
    part[tid] += v;
    __syncthreads();
  }
  int base = (tid == 0) ? 0 : part[tid - 1];
  for (int i = lo; i < hi; ++i) { offs[i] = base; base += deg[i]; }
  if (tid == 1023) offs[NSEG] = base;               // total = NED
}

__global__ __launch_bounds__(256) void k_csr_fill(
    const int* __restrict__ eidx, const int* __restrict__ offs,
    int* __restrict__ cur, int* __restrict__ val)
{
  const int gid = blockIdx.x * 256 + threadIdx.x;   // grid = NED/256
  const int e   = gid / PNE;
  const int j   = gid - e * PNE;
  const int src = eidx[(size_t)e * 2 * PNE + j];
  const int dst = eidx[(size_t)e * 2 * PNE + PNE + j];
  const int dT  = (e < 5) ? 0 : e - 4;
  const int seg = dT * PN + dst;
  const int pos = offs[seg] + atomicAdd(&cur[seg], 1);
  val[pos] = e * PN + src;                          // packed: directly indexes ktr/vtr rows
}

// ---------------------------------------------------------------------------
// Fused edge attention: one wave per segment. No global atomics, no init.
// ---------------------------------------------------------------------------
#define ACAP 256

template <int H>
__global__ __launch_bounds__(256) void k_attn_fused(
    const float* __restrict__ q,       // [NSEG][H]
    const float* __restrict__ ktr,     // [(e*PN+src)][H]
    const float* __restrict__ vtr,
    const int*   __restrict__ offs,
    const int*   __restrict__ csr_val,
    const float* __restrict__ p_rel,
    float*       __restrict__ agg)     // [NSEG][H]
{
  const int seg  = blockIdx.x * 4 + (threadIdx.x >> 6);
  const int lane = threadIdx.x & 63;
  const int wv   = threadIdx.x >> 6;
  constexpr int PL = H / 64;           // floats per lane
  const float scale = 1.0f / sqrtf((float)H);

  __shared__ float salpha[4][ACAP];
  float* lalpha = salpha[wv];

  const float* qrow = q + (size_t)seg * H;
  float qr[PL];
  #pragma unroll
  for (int p = 0; p < PL; ++p) qr[p] = qrow[lane + 64 * p];

  const int start = offs[seg];
  const int deg   = offs[seg + 1] - start;

  // pass 1: alphas + running max (alpha broadcast to all lanes via butterfly)
  float m = -INFINITY;
  for (int i = 0; i < deg; ++i) {
    const int val = csr_val[start + i];
    const int e   = val / PN;
    const float* krow = ktr + (size_t)val * H;
    float d = 0.f;
    #pragma unroll
    for (int p = 0; p < PL; ++p) d += qr[p] * krow[lane + 64 * p];
    #pragma unroll
    for (int off = 32; off > 0; off >>= 1) d += __shfl_xor(d, off);
    const float al = d * p_rel[e] * scale;
    if (i < ACAP && lane == 0) lalpha[i] = al;
    m = fmaxf(m, al);
  }

  // pass 2: exp, sum, weighted-V accumulate
  float acc[PL];
  #pragma unroll
  for (int p = 0; p < PL; ++p) acc[p] = 0.f;
  float s = 0.f;
  for (int i = 0; i < deg; ++i) {
    const int val = csr_val[start + i];
    float al;
    if (i < ACAP) {
      al = lalpha[i];
    } else {                            // fallback (deg > 256: practically never)
      const int e = val / PN;
      const float* krow = ktr + (size_t)val * H;
      float d = 0.f;
      #pragma unroll
      for (int p = 0; p < PL; ++p) d += qr[p] * krow[lane + 64 * p];
      #pragma unroll
      for (int off = 32; off > 0; off >>= 1) d += __shfl_xor(d, off);
      al = d * p_rel[e] * scale;
    }
    const float ev = expf(al - m);
    s += ev;
    const float* vrow = vtr + (size_t)val * H;
    #pragma unroll
    for (int p = 0; p < PL; ++p) acc[p] += ev * vrow[lane + 64 * p];
  }

  const float inv = 1.0f / (s + 1e-16f);
  float* arow = agg + (size_t)seg * H;
  #pragma unroll
  for (int p = 0; p < PL; ++p) arow[lane + 64 * p] = acc[p] * inv;
}

// epilogue: tanh -> rel/all_rep, logits = all_rep @ W3 + b3.  one wave per row.
__global__ __launch_bounds__(256) void k_final(
    const float* __restrict__ h2, const float* __restrict__ W3,
    const float* __restrict__ b3, float* __restrict__ out)
{
  const int row = blockIdx.x * 4 + (threadIdx.x >> 6);
  if (row >= PT * PN) return;
  const int lane = threadIdx.x & 63;

  const float v = tanhf(h2[(size_t)row * PH2 + lane]);
  out[(size_t)PN * PH2 + (size_t)row * PH2 + lane] = v;      // all_rep
  if (row < PN) out[(size_t)row * PH2 + lane] = v;           // rel

  float l[PC];
  #pragma unroll
  for (int c = 0; c < PC; ++c) l[c] = v * W3[lane * PC + c];
  #pragma unroll
  for (int c = 0; c < PC; ++c) {
    #pragma unroll
    for (int off = 32; off > 0; off >>= 1) l[c] += __shfl_xor(l[c], off);
  }
  if (lane == 0) {
    const size_t lo = (size_t)PN * PH2 + (size_t)PT * PN * PH2;
    #pragma unroll
    for (int c = 0; c < PC; ++c) out[lo + (size_t)row * PC + c] = l[c] + b3[c];
  }
}

// diagnostic fallback: ws too small -> deterministic zero output (no OOB, no crash)
__global__ __launch_bounds__(256) void k_out_zero(float* __restrict__ out, long n)
{
  const long i = (long)blockIdx.x * 256 + threadIdx.x;
  if (i < n) out[i] = 0.f;
}

// ---------------------------------------------------------------------------
extern "C" void kernel_launch(void* const* d_in, const int* in_sizes, int n_in,
                              void* d_out, int out_size, void* d_ws, size_t ws_size,
                              hipStream_t stream)
{
  const float* x      = (const float*)d_in[0];
  const int*   eidx   = (const int*)  d_in[1];
  const float* Wkqv1  = (const float*)d_in[2];
  const float* bkqv1  = (const float*)d_in[3];
  const float* a1     = (const float*)d_in[4];
  const float* m1     = (const float*)d_in[5];
  const float* p1     = (const float*)d_in[6];
  const float* Wout1  = (const float*)d_in[7];
  const float* bout1  = (const float*)d_in[8];
  const float* Wkqv2  = (const float*)d_in[9];
  const float* bkqv2  = (const float*)d_in[10];
  const float* a2     = (const float*)d_in[11];
  const float* m2     = (const float*)d_in[12];
  const float* p2     = (const float*)d_in[13];
  const float* Wout2  = (const float*)d_in[14];
  const float* bout2  = (const float*)d_in[15];
  const float* W3     = (const float*)d_in[16];
  const float* b3     = (const float*)d_in[17];
  float* out = (float*)d_out;

  // -------- tight workspace layout: 332.3 MB total --------
  const size_t SZ_A = (size_t)PE * PN * PH1 * 4;     // 102,400,000
  const size_t SZ_B = SZ_A;
  const size_t SZ_C = (size_t)PT * PN * PH1 * 4;     //  61,440,000
  const size_t SZ_D = SZ_C;
  const size_t R_A = 0;
  const size_t R_B = R_A + SZ_A;
  const size_t R_C = R_B + SZ_B;
  const size_t R_D = R_C + SZ_C;
  const size_t R_deg  = R_D + SZ_D;
  const size_t R_offs = R_deg  + (size_t)NSEG * 4;
  const size_t R_cur  = R_offs + (size_t)(NSEG + 1) * 4;
  const size_t R_val  = R_cur  + (size_t)NSEG * 4;
  const size_t NEED   = R_val + (size_t)NED * 4;     // 332,320,004 bytes

  if (ws_size < NEED) {                              // diagnostic: clean fail, no OOB
    const long n = out_size;
    k_out_zero<<<dim3((unsigned)((n + 255) / 256)), dim3(256), 0, stream>>>(out, n);
    return;
  }

  char* ws = (char*)d_ws;
  float* bufA = (float*)(ws + R_A);
  float* bufB = (float*)(ws + R_B);
  float* bufC = (float*)(ws + R_C);
  float* bufD = (float*)(ws + R_D);
  int*   deg  = (int*)  (ws + R_deg);
  int*   offs = (int*)  (ws + R_offs);
  int*   cur  = (int*)  (ws + R_cur);
  int*   cval = (int*)  (ws + R_val);

  const dim3 blk(256);
  const int  mt = (PN + 63) / 64;              // 313 row tiles

  // ---------------- CSR build (shared by both layers) ----------------
  k_csr_zero <<<dim3((NSEG + 255) / 256), blk, 0, stream>>>(deg, cur);
  k_csr_count<<<dim3(NED / 256), blk, 0, stream>>>(eidx, deg);
  k_csr_scan <<<dim3(1), dim3(1024), 0, stream>>>(deg, offs);
  k_csr_fill <<<dim3(NED / 256), blk, 0, stream>>>(eidx, offs, cur, cval);

  // ---------------- Layer 1 (H=128) ----------------
  // k1 -> C ; ktr1 -> A ; v1 -> C ; vtr1 -> B ; q1 -> C ; attn -> D ; x2 -> C
  k_gemm_slice<<<dim3(mt, PH1 / 64, PT), blk, 0, stream>>>(x, Wkqv1, bkqv1, bufC, PN, PIN, 3 * PH1, 0, PH1);
  k_gemm_rel  <<<dim3(mt, PH1 / 64, PE), blk, 0, stream>>>(bufC, a1, bufA, PN, PH1);
  k_gemm_slice<<<dim3(mt, PH1 / 64, PT), blk, 0, stream>>>(x, Wkqv1, bkqv1, bufC, PN, PIN, 3 * PH1, 2, PH1);
  k_gemm_rel  <<<dim3(mt, PH1 / 64, PE), blk, 0, stream>>>(bufC, m1, bufB, PN, PH1);
  k_gemm_slice<<<dim3(mt, PH1 / 64, PT), blk, 0, stream>>>(x, Wkqv1, bkqv1, bufC, PN, PIN, 3 * PH1, 1, PH1);
  k_attn_fused<PH1><<<dim3(NSEG / 4), blk, 0, stream>>>(bufC, bufA, bufB, offs, cval, p1, bufD);
  k_gemm_out  <<<dim3(mt, PH1 / 64, PT), blk, 0, stream>>>(bufD, Wout1, bout1, bufC, PN, PH1);

  // ---------------- Layer 2 (H=64), x2 in C ----------------
  k_gemm_slice<<<dim3(mt, PH2 / 64, PT), blk, 0, stream>>>(bufC, Wkqv2, bkqv2, bufD, PN, PH1, 3 * PH2, 0, PH2);
  k_gemm_rel  <<<dim3(mt, PH2 / 64, PE), blk, 0, stream>>>(bufD, a2, bufA, PN, PH2);
  k_gemm_slice<<<dim3(mt, PH2 / 64, PT), blk, 0, stream>>>(bufC, Wkqv2, bkqv2, bufD, PN, PH1, 3 * PH2, 2, PH2);
  k_gemm_rel  <<<dim3(mt, PH2 / 64, PE), blk, 0, stream>>>(bufD, m2, bufB, PN, PH2);
  k_gemm_slice<<<dim3(mt, PH2 / 64, PT), blk, 0, stream>>>(bufC, Wkqv2, bkqv2, bufD, PN, PH1, 3 * PH2, 1, PH2);
  k_attn_fused<PH2><<<dim3(NSEG / 4), blk, 0, stream>>>(bufD, bufA, bufB, offs, cval, p2, bufC);
  k_gemm_out  <<<dim3(mt, PH2 / 64, PT), blk, 0, stream>>>(bufC, Wout2, bout2, bufD, PN, PH2);

  // ---------------- Epilogue ----------------
  k_final<<<dim3((PT * PN + 3) / 4), blk, 0, stream>>>(bufD, W3, b3, out);
}